// Round 10
// baseline (29.130 us; speedup 1.0000x reference)
//
#include <hip/hip_runtime.h>

// SSIM loss, N=64 images, 1 ch, 384x384 f32, 7x7 box, VALID -> 378x378. out = -mean(S).
//
// R10 = R9's batched prefix/suffix shuffles with the slot arithmetic FIXED.
// R9 bug: add-first flow but R8's slot discipline (write slot i, 7-row
// prologue) -> windows drifted one row after step 0. Correct add-first flow
// (R7's): sums enter each step with 6 rows; prologue accumulates k<6 only;
// new row r0+s+6 is written to slot (i+6)%7; old row r0+s subtracted from
// slot i%7 (s=7kk+i, and 7kk mod 7 = 0 so slots depend only on i).
//
// Hypothesis under test (from R9): R8 consumed each __shfl_down immediately
// (24x issue->wait->use per step = naked LDS-pipe latency ~1700cy/step at
// 1.7 waves/SIMD). Here all 24 shuffles issue as one batch, then ~100
// independent VALU insts (subtract-old, history write, rotate, prefetch)
// cover their latency, then combine O[j] = CS[j] + NP[j].
//  - lane owns cols 6l..6l+5 (64*6=384), RB=14 rows/band, 27x64=1728 waves
//  - 7-deep raw register history, statically indexed (7-step inner unroll)
//  - 2-deep new-row prefetch; outer kk loop rolled (I$, R8 win); t34 merge

constexpr int IND   = 384;
constexpr int OUTD  = 378;
constexpr int RB    = 14;            // output rows per band
constexpr int BANDS = OUTD / RB;     // 27
constexpr int CPL   = 6;             // cols per lane

using f32x2 = __attribute__((ext_vector_type(2))) float;

__global__ __launch_bounds__(64, 2)
void ssim_band(const float* __restrict__ X, const float* __restrict__ Y,
               const float* __restrict__ MX, float* __restrict__ blocksum)
{
    const int band = blockIdx.x;
    const int n    = blockIdx.y;
    const int lane = threadIdx.x;
    const int c0   = lane * CPL;
    const int r0   = band * RB;      // input rows r0..r0+19, all <= 383

    const float* __restrict__ Xp = X + (size_t)n * (IND * IND) + c0;
    const float* __restrict__ Yp = Y + (size_t)n * (IND * IND) + c0;

    float hx[7][CPL], hy[7][CPL];                  // raw row history
    float sx[CPL]  = {}, sy[CPL]  = {};
    float sxx[CPL] = {}, syy[CPL] = {}, sxy[CPL] = {};

#define LOADROW(DX, DY, R) {                                                  \
    const float* _px = Xp + (size_t)(R) * IND;                                \
    const float* _py = Yp + (size_t)(R) * IND;                                \
    f32x2 _a = *(const f32x2*)_px;                                            \
    f32x2 _b = *(const f32x2*)(_px + 2);                                      \
    f32x2 _c = *(const f32x2*)(_px + 4);                                      \
    f32x2 _d = *(const f32x2*)_py;                                            \
    f32x2 _e = *(const f32x2*)(_py + 2);                                      \
    f32x2 _f = *(const f32x2*)(_py + 4);                                      \
    DX[0]=_a.x; DX[1]=_a.y; DX[2]=_b.x; DX[3]=_b.y; DX[4]=_c.x; DX[5]=_c.y;   \
    DY[0]=_d.x; DY[1]=_d.y; DY[2]=_e.x; DY[3]=_e.y; DY[4]=_f.x; DY[5]=_f.y; }

    // ---- prologue: rows r0..r0+5 -> slots 0..5 AND sums (6 rows only);
    //      pax = row r0+6, pbx = row r0+7 ----
#pragma unroll
    for (int k = 0; k < 6; ++k) LOADROW(hx[k], hy[k], r0 + k)

    float pax[CPL], pay[CPL], pbx[CPL], pby[CPL];
    LOADROW(pax, pay, r0 + 6)
    LOADROW(pbx, pby, r0 + 7)

#pragma unroll
    for (int k = 0; k < 6; ++k)
#pragma unroll
        for (int c = 0; c < CPL; ++c) {
            float x = hx[k][c], y = hy[k][c];
            sx[c] += x;  sy[c] += y;
            sxx[c] = fmaf(x, x, sxx[c]);
            syy[c] = fmaf(y, y, syy[c]);
            sxy[c] = fmaf(x, y, sxy[c]);
        }

    const float m   = MX[n];
    const float c1  = (0.01f * m) * (0.01f * m);
    const float c2  = (0.03f * m) * (0.03f * m);
    const float k1  = 2401.0f * c1;      // 49^2 * C1
    const float k2  = 2401.0f * c2;
    const float cn  = 49.0f / 48.0f;
    const float cn2 = 2.0f * cn;

    // Prefix/suffix horizontal window (own cols j..5 + neighbor cols 0..j):
    //   p_k = S[0]+..+S[k-1];  NP[j] = shfl_down(p_{j+1}, 1)
    //   CS[j] = S[j]+..+S[5];  O[j] = CS[j] + NP[j]
#define PHASE_A(S, NP, CS) {                                                  \
    float _p1 = S[0];                                                         \
    float _p2 = _p1 + S[1];                                                   \
    float _p3 = _p2 + S[2];                                                   \
    float _p4 = _p3 + S[3];                                                   \
    float _p5 = _p4 + S[4];                                                   \
    float _p6 = _p5 + S[5];                                                   \
    NP[0] = __shfl_down(_p1, 1);                                              \
    NP[1] = __shfl_down(_p2, 1);                                              \
    NP[2] = __shfl_down(_p3, 1);                                              \
    NP[3] = __shfl_down(_p4, 1);                                              \
    NP[4] = __shfl_down(_p5, 1);                                              \
    NP[5] = __shfl_down(_p6, 1);                                              \
    CS[5] = S[5];                                                             \
    CS[4] = S[4] + S[5];                                                      \
    CS[3] = S[3] + CS[4];                                                     \
    CS[2] = S[2] + CS[3];                                                     \
    CS[1] = S[1] + CS[2];                                                     \
    CS[0] = _p6; }

    float partial = 0.f;

#pragma unroll 1                       // keep the 7-step body I$-resident
    for (int kk = 0; kk < RB / 7; ++kk) {
#pragma unroll
        for (int i = 0; i < 7; ++i) {
            const int os = i;                // old-row slot: row r0+s
            const int ws = (i + 6) % 7;      // new-row slot: row r0+s+6

            // ---- 1. add new row r0+s+6 (pax); window complete (7 rows) ----
#pragma unroll
            for (int c = 0; c < CPL; ++c) {
                float nx = pax[c], ny = pay[c];
                sx[c] += nx;  sy[c] += ny;
                sxx[c] = fmaf(nx, nx, sxx[c]);
                syy[c] = fmaf(ny, ny, syy[c]);
                sxy[c] = fmaf(nx, ny, sxy[c]);
            }
            float u[CPL];
#pragma unroll
            for (int c = 0; c < CPL; ++c) u[c] = sxx[c] + syy[c];

            // ---- 2. batch-issue all 24 shuffles; capture suffixes ----
            float np1[CPL], np2[CPL], np5[CPL], np34[CPL];
            float cs1[CPL], cs2[CPL], cs5[CPL], cs34[CPL];
            PHASE_A(sx,  np1,  cs1)
            PHASE_A(sy,  np2,  cs2)
            PHASE_A(sxy, np5,  cs5)
            PHASE_A(u,   np34, cs34)

            // ---- 3. cover work: subtract old row (slot os), record new row
            //         (slot ws), rotate pipe, prefetch row r0+s+8 ----
#pragma unroll
            for (int c = 0; c < CPL; ++c) {
                float ox = hx[os][c], oy = hy[os][c];
                float nx = pax[c],    ny = pay[c];
                sx[c] -= ox;  sy[c] -= oy;
                sxx[c] = fmaf(-ox, ox, sxx[c]);
                syy[c] = fmaf(-oy, oy, syy[c]);
                sxy[c] = fmaf(-ox, oy, sxy[c]);
                hx[ws][c] = nx;  hy[ws][c] = ny;
                pax[c] = pbx[c]; pay[c] = pby[c];
            }
            {
                int nr = r0 + 7 * kk + i + 8;      // pbx refill (2 ahead)
                if (nr > IND - 1) nr = IND - 1;    // tail: harmless clamp
                LOADROW(pbx, pby, nr)
            }

            // ---- 4. combine windows; SSIM formula (49^4-scaled) ----
            if (lane < 63) {
#pragma unroll
                for (int c = 0; c < CPL; ++c) {
                    float t1  = cs1[c]  + np1[c];
                    float t2  = cs2[c]  + np2[c];
                    float t5  = cs5[c]  + np5[c];
                    float t34 = cs34[c] + np34[c];
                    float pxy = t1 * t2;
                    float ss  = fmaf(t1, t1, t2 * t2);
                    float A1  = fmaf(2.f, pxy, k1);
                    float B1  = ss + k1;
                    float A2  = fmaf(cn2, fmaf(49.f, t5, -pxy), k2);
                    float B2  = fmaf(cn, fmaf(49.f, t34, -ss), k2);
                    partial += __fdividef(A1 * A2, B1 * B2);
                }
            }
        }
    }
#undef PHASE_A
#undef LOADROW

    // ---- wave reduction (deterministic) ----
#pragma unroll
    for (int off = 32; off; off >>= 1) partial += __shfl_down(partial, off);
    if (lane == 0) blocksum[(size_t)n * BANDS + band] = partial;
}

__global__ __launch_bounds__(256)
void ssim_reduce(const float* __restrict__ blocksum, float* __restrict__ out,
                 int nblocks, float inv_npix)
{
    const int tid = threadIdx.x;
    float s = 0.f;
    for (int i = tid; i < nblocks; i += 256) s += blocksum[i];
#pragma unroll
    for (int off = 32; off; off >>= 1) s += __shfl_down(s, off);
    __shared__ float ws[4];
    if ((tid & 63) == 0) ws[tid >> 6] = s;
    __syncthreads();
    if (tid == 0) out[0] = -(ws[0] + ws[1] + ws[2] + ws[3]) * inv_npix;
}

extern "C" void kernel_launch(void* const* d_in, const int* in_sizes, int n_in,
                              void* d_out, int out_size, void* d_ws, size_t ws_size,
                              hipStream_t stream)
{
    const float* X  = (const float*)d_in[0];
    const float* Y  = (const float*)d_in[1];
    // d_in[2] = norm (unused by reference), d_in[4] = w (ones/49, baked in)
    const float* MX = (const float*)d_in[3];

    const int N       = in_sizes[3];             // 64
    const int nblocks = N * BANDS;               // 1728

    float* bs = (float*)d_ws;

    dim3 grid(BANDS, N);
    ssim_band<<<grid, 64, 0, stream>>>(X, Y, MX, bs);

    const float inv_npix = 1.0f / ((float)N * OUTD * OUTD);
    ssim_reduce<<<1, 256, 0, stream>>>(bs, (float*)d_out, nblocks, inv_npix);
}